// Round 3
// baseline (171.596 us; speedup 1.0000x reference)
//
#include <hip/hip_runtime.h>
#include <math.h>

#define NB 4
#define NPRED 8400
#define NGT 32
#define NCLS 80
#define ROW 85
#define NSEG 132   // ceil(8400/64)

// ---------- math helpers (mirror reference fp32 op order) ----------

__device__ __forceinline__ float focal_t(float x, float t) {
    float p = 1.f / (1.f + expf(-x));
    float ce = (fmaxf(x, 0.f) + log1pf(expf(-fabsf(x)))) - x * t; // logaddexp(0,x) - x*t
    float pt = p * t + (1.f - p) * (1.f - t);
    float ompt = 1.f - pt;
    float loss = ce * (ompt * ompt);              // GAMMA=2
    float at = 0.25f * t + 0.75f * (1.f - t);     // ALPHA=0.25
    return at * loss;
}

__device__ __forceinline__ float ciou_f(float x1, float y1, float x2, float y2,
                                        float x1g, float y1g, float x2g, float y2g,
                                        float atan_p, float atan_g) {
    float w1 = x2 - x1, h1 = y2 - y1;
    float wg = x2g - x1g, hg = y2g - y1g;
    float iw = fmaxf(fminf(x2, x2g) - fmaxf(x1, x1g), 0.f);
    float ih = fmaxf(fminf(y2, y2g) - fmaxf(y1, y1g), 0.f);
    float inter = iw * ih;
    float uni = w1 * h1 + wg * hg - inter;
    float iou = inter / (uni + 1e-7f);
    float cw = fmaxf(x2, x2g) - fminf(x1, x1g);
    float ch = fmaxf(y2, y2g) - fminf(y1, y1g);
    float diag = cw * cw + ch * ch + 1e-7f;
    float dx = (x1 + x2 - x1g - x2g) * 0.5f;
    float dy = (y1 + y2 - y1g - y2g) * 0.5f;
    float rho2 = dx * dx + dy * dy;
    float diou = 1.f - iou + rho2 / diag;
    float dd = atan_g - atan_p;
    const float CV = (float)(4.0 / (M_PI * M_PI));
    float v = CV * (dd * dd);
    float alpha = v / (1.f - iou + v + 1e-7f);
    return diou + alpha * v;
}

// ---------- K0: zero neg buckets + precompute GT geometry/labels ----------

__global__ __launch_bounds__(128) void init_kernel(
        const float* __restrict__ targets, double* __restrict__ buckets,
        float* __restrict__ gtab, int* __restrict__ larr) {
    int t = threadIdx.x;           // 128 = 4 b x 32 m
    if (t < 64) buckets[t] = 0.0;
    int b = t >> 5, m = t & 31;
    const float* gt = targets + (size_t)(b * NGT + m) * ROW;
    float xc = gt[0], yc = gt[1], w = gt[2], h = gt[3];
    float x1 = xc - w * 0.5f, y1 = yc - h * 0.5f;
    float x2 = xc + w * 0.5f, y2 = yc + h * 0.5f;
    float* gp = gtab + (size_t)(b * NGT + m) * 8;
    gp[0] = x1; gp[1] = y1; gp[2] = x2; gp[3] = y2;
    gp[4] = atanf((x2 - x1) / (y2 - y1));
    int lab = 0;
    for (int c = 0; c < NCLS; ++c) {
        if (gt[5 + c] > 0.5f) { lab = c; break; }
    }
    larr[b * NGT + m] = lab;
}

// ---------- K1: wave-per-pred S0 (coalesced class reads) + neg sum ----------

__global__ __launch_bounds__(256) void s0_kernel(
        const float* __restrict__ outputs, float* __restrict__ s0arr,
        double* __restrict__ buckets) {
    __shared__ double s_neg[4];
    int b = blockIdx.y;
    int wid = threadIdx.x >> 6, lane = threadIdx.x & 63;
    int n = blockIdx.x * 4 + wid;              // gridDim.x = 2100, exact
    const float* pr = outputs + (size_t)(b * NPRED + n) * ROW;

    float s = focal_t(pr[5 + lane], 0.f);      // classes lane and lane+64
    if (lane < 16) s += focal_t(pr[69 + lane], 0.f);
    #pragma unroll
    for (int off = 32; off >= 1; off >>= 1) s += __shfl_xor(s, off);

    if (lane == 0) {
        s0arr[b * NPRED + n] = s;
        s_neg[wid] = (double)focal_t(pr[4], 0.f);
    }
    __syncthreads();
    if (threadIdx.x == 0) {
        double t = s_neg[0] + s_neg[1] + s_neg[2] + s_neg[3];
        atomicAdd(&buckets[blockIdx.x & 63], t);
    }
}

// ---------- K2: cost matrix + per-(row,segment) minima, m split 4-way ----------

__global__ __launch_bounds__(256) void cost_kernel(
        const float* __restrict__ outputs, const float* __restrict__ s0arr,
        const float* __restrict__ gtab, const int* __restrict__ larr,
        float* __restrict__ costT, float* __restrict__ segval,
        int* __restrict__ segidx) {
    int b = blockIdx.z;
    int mbase = blockIdx.y * 8;
    int tid = threadIdx.x;
    int n = blockIdx.x * 256 + tid;
    bool valid = (n < NPRED);
    int seg = n >> 6;

    const float* pr = outputs + (size_t)(b * NPRED + (valid ? n : 0)) * ROW;
    float x1 = 0.f, y1 = 0.f, x2 = 0.f, y2 = 0.f, atan_p = 0.f, S0 = 0.f;
    if (valid) {
        float xc = pr[0], yc = pr[1], w = pr[2], h = pr[3];
        x1 = xc - w * 0.5f; y1 = yc - h * 0.5f;
        x2 = xc + w * 0.5f; y2 = yc + h * 0.5f;
        atan_p = atanf((x2 - x1) / (y2 - y1));
        S0 = s0arr[b * NPRED + n];
    }

    #pragma unroll
    for (int k = 0; k < 8; ++k) {
        int m = mbase + k;
        const float* gp = gtab + (size_t)(b * NGT + m) * 8;
        float cost = INFINITY;
        if (valid) {
            float cc = ciou_f(x1, y1, x2, y2, gp[0], gp[1], gp[2], gp[3],
                              atan_p, gp[4]);
            int lab = larr[b * NGT + m];
            float xl = pr[5 + lab];
            cost = cc + (S0 - focal_t(xl, 0.f) + focal_t(xl, 1.f)) / 80.f;
            costT[(size_t)(b * NGT + m) * NPRED + n] = cost;
        }
        float v = cost; int ci = valid ? n : NPRED;
        #pragma unroll
        for (int off = 32; off >= 1; off >>= 1) {
            float ov = __shfl_xor(v, off);
            int oi = __shfl_xor(ci, off);
            if (ov < v || (ov == v && oi < ci)) { v = ov; ci = oi; }
        }
        if ((tid & 63) == 0) {
            segval[(size_t)(b * NGT + m) * NSEG + seg] = v;
            segidx[(size_t)(b * NGT + m) * NSEG + seg] = ci;
        }
    }
}

// ---------- K3: assignment, single wave per batch (no barriers) ----------
// Same effective semantics as the reference "hungarian" (see round-0 note).

__global__ __launch_bounds__(64) void assign_kernel(
        const float* __restrict__ costT, const float* __restrict__ segval,
        const int* __restrict__ segidx, int* __restrict__ midx) {
    int b = blockIdx.x;
    int lane = threadIdx.x;
    __shared__ float sv[NGT * NSEG];
    __shared__ int   si[NGT * NSEG];
    __shared__ unsigned char state[NPRED];   // 0 free, 1 assigned, 2 poisoned
    __shared__ unsigned char dirty[NSEG];
    __shared__ int s_midx[NGT];

    for (int k = lane; k < NGT * NSEG; k += 64) {
        sv[k] = segval[(size_t)b * NGT * NSEG + k];
        si[k] = segidx[(size_t)b * NGT * NSEG + k];
    }
    unsigned int* st32 = (unsigned int*)state;
    for (int k = lane; k < NPRED / 4; k += 64) st32[k] = 0u;
    for (int k = lane; k < NSEG; k += 64) dirty[k] = 0;

    const float* C = costT + (size_t)b * NGT * NPRED;

    for (int i = 0; i < NGT; ++i) {
        // argmin over 132 segment minima (value, lowest col)
        float v = INFINITY; int ci = NPRED;
        for (int s = lane; s < NSEG; s += 64) {
            float vv = sv[i * NSEG + s]; int ii = si[i * NSEG + s];
            if (vv < v || (vv == v && ii < ci)) { v = vv; ci = ii; }
        }
        #pragma unroll
        for (int off = 32; off >= 1; off >>= 1) {
            float ov = __shfl_xor(v, off);
            int oi = __shfl_xor(ci, off);
            if (ov < v || (ov == v && oi < ci)) { v = ov; ci = oi; }
        }
        int j1 = ci;                          // uniform across wave
        int st = state[j1];
        if (st == 0) {
            if (lane == 0) { state[j1] = 1; s_midx[i] = j1; }
        } else {
            // collision: poison j1, walk to first free col poisoning assigned
            if (lane == 0) { state[j1] = 2; dirty[j1 >> 6] = 1; }
            int jf = 0;
            for (int k0 = 0; k0 < NPRED; k0 += 64) {
                int col = k0 + lane;
                unsigned long long mask = __ballot(col < NPRED && state[col] == 0);
                if (mask) { jf = k0 + (__ffsll((unsigned long long)mask) - 1); break; }
            }
            for (int j = lane; j < jf; j += 64) {
                if (state[j] == 1) { state[j] = 2; dirty[j >> 6] = 1; }
            }
            if (lane == 0) { state[jf] = 1; s_midx[i] = jf; }
            // rescan dirty segments for all rows (exclude state==2 only)
            for (int k0 = 0; k0 < NSEG; k0 += 64) {
                int sgl = k0 + lane;
                unsigned long long dm = __ballot(sgl < NSEG && dirty[sgl]);
                while (dm) {
                    int sg = k0 + (__ffsll(dm) - 1);
                    dm &= dm - 1;
                    int col = (sg << 6) + lane;
                    bool cv = (col < NPRED) && (state[col] != 2);
                    for (int r = 0; r < NGT; ++r) {
                        float vv = cv ? C[(size_t)r * NPRED + col] : INFINITY;
                        int ii = cv ? col : NPRED;
                        #pragma unroll
                        for (int off = 32; off >= 1; off >>= 1) {
                            float ov = __shfl_xor(vv, off);
                            int oi = __shfl_xor(ii, off);
                            if (ov < vv || (ov == vv && oi < ii)) { vv = ov; ii = oi; }
                        }
                        if (lane == 0) { sv[r * NSEG + sg] = vv; si[r * NSEG + sg] = ii; }
                    }
                    if (lane == 0) dirty[sg] = 0;
                }
            }
        }
    }
    if (lane < NGT) midx[b * NGT + lane] = s_midx[lane];
}

// ---------- K4: finalize ----------

__global__ __launch_bounds__(128) void finalize_kernel(
        const float* __restrict__ outputs, const float* __restrict__ targets,
        const int* __restrict__ midx, const double* __restrict__ buckets,
        float* __restrict__ out) {
    __shared__ float s_siou[128], s_cls[128], s_adj[128];
    int t = threadIdx.x;
    int b = t >> 5, m = t & 31;

    const float* gt = targets + (size_t)(b * NGT + m) * ROW;
    int j = midx[b * NGT + m];
    const float* pr = outputs + (size_t)(b * NPRED + j) * ROW;

    float xc = pr[0], yc = pr[1], w = pr[2], h = pr[3];
    float x1 = xc - w * 0.5f, y1 = yc - h * 0.5f;
    float x2 = xc + w * 0.5f, y2 = yc + h * 0.5f;
    float atan_p = atanf((x2 - x1) / (y2 - y1));
    float gxc = gt[0], gyc = gt[1], gw = gt[2], gh = gt[3];
    float x1g = gxc - gw * 0.5f, y1g = gyc - gh * 0.5f;
    float x2g = gxc + gw * 0.5f, y2g = gyc + gh * 0.5f;
    float atan_g = atanf((x2g - x1g) / (y2g - y1g));

    s_siou[t] = ciou_f(x1, y1, x2, y2, x1g, y1g, x2g, y2g, atan_p, atan_g);

    float cls_sum = 0.f;
    for (int c = 0; c < NCLS; ++c) cls_sum += focal_t(pr[5 + c], gt[5 + c]);
    s_cls[t] = cls_sum / 80.f;

    float conf = pr[4];
    s_adj[t] = focal_t(conf, 1.f) - focal_t(conf, 0.f);
    __syncthreads();

    if (t == 0) {
        double nsum = 0.0;
        for (int k = 0; k < 64; ++k) nsum += buckets[k];
        double ssum = 0.0, csum = 0.0, asum = 0.0;
        for (int k = 0; k < 128; ++k) {
            ssum += (double)s_siou[k];
            csum += (double)s_cls[k];
            asum += (double)s_adj[k];
        }
        float siou = (float)(ssum / 128.0);
        float cls  = (float)(csum / 128.0);
        float obj  = (float)((nsum + asum) / (double)(NB * NPRED));
        out[0] = 2.0f * siou + 2.0f * obj + 2.0f * cls;
        out[1] = siou;
        out[2] = obj;
        out[3] = cls;
    }
}

// ---------- launch ----------

extern "C" void kernel_launch(void* const* d_in, const int* in_sizes, int n_in,
                              void* d_out, int out_size, void* d_ws, size_t ws_size,
                              hipStream_t stream) {
    const float* outputs = (const float*)d_in[0];
    const float* targets = (const float*)d_in[1];
    float* out = (float*)d_out;

    char* ws = (char*)d_ws;
    double* buckets = (double*)ws;                      // 64*8 = 512 B
    int* midx = (int*)(ws + 512);                       // 512 B
    float* gtab = (float*)(ws + 1024);                  // 4*32*8*4 = 4096 B
    int* larr = (int*)(ws + 5120);                      // 512 B
    float* s0arr = (float*)(ws + 6144);                 // 33600*4 = 134400 B
    float* segval = (float*)(ws + 140544);              // 67584 B
    int* segidx = (int*)(ws + 208128);                  // 67584 B
    float* costT = (float*)(ws + 275712);               // 4300800 B  (total ~4.58 MB)

    init_kernel<<<1, 128, 0, stream>>>(targets, buckets, gtab, larr);

    dim3 g1(NPRED / 4, NB);                             // 2100 x 4, wave-per-pred
    s0_kernel<<<g1, 256, 0, stream>>>(outputs, s0arr, buckets);

    dim3 g2((NPRED + 255) / 256, NGT / 8, NB);          // 33 x 4 x 4
    cost_kernel<<<g2, 256, 0, stream>>>(outputs, s0arr, gtab, larr,
                                        costT, segval, segidx);

    assign_kernel<<<NB, 64, 0, stream>>>(costT, segval, segidx, midx);

    finalize_kernel<<<1, 128, 0, stream>>>(outputs, targets, midx, buckets, out);
}

// Round 4
// 127.531 us; speedup vs baseline: 1.3455x; 1.3455x over previous
//
#include <hip/hip_runtime.h>
#include <math.h>

#define NB 4
#define NPRED 8400
#define NGT 32
#define NCLS 80
#define ROW 85
#define NSEG 132    // ceil(8400/64)
#define NSEGP 133   // padded LDS row stride (breaks bank alignment)

// ---------- math helpers (mirror reference fp32 op order) ----------

__device__ __forceinline__ float focal_t(float x, float t) {
    float p = 1.f / (1.f + expf(-x));
    float ce = (fmaxf(x, 0.f) + log1pf(expf(-fabsf(x)))) - x * t; // logaddexp(0,x) - x*t
    float pt = p * t + (1.f - p) * (1.f - t);
    float ompt = 1.f - pt;
    float loss = ce * (ompt * ompt);              // GAMMA=2
    float at = 0.25f * t + 0.75f * (1.f - t);     // ALPHA=0.25
    return at * loss;
}

__device__ __forceinline__ float ciou_f(float x1, float y1, float x2, float y2,
                                        float x1g, float y1g, float x2g, float y2g,
                                        float atan_p, float atan_g) {
    float w1 = x2 - x1, h1 = y2 - y1;
    float wg = x2g - x1g, hg = y2g - y1g;
    float iw = fmaxf(fminf(x2, x2g) - fmaxf(x1, x1g), 0.f);
    float ih = fmaxf(fminf(y2, y2g) - fmaxf(y1, y1g), 0.f);
    float inter = iw * ih;
    float uni = w1 * h1 + wg * hg - inter;
    float iou = inter / (uni + 1e-7f);
    float cw = fmaxf(x2, x2g) - fminf(x1, x1g);
    float ch = fmaxf(y2, y2g) - fminf(y1, y1g);
    float diag = cw * cw + ch * ch + 1e-7f;
    float dx = (x1 + x2 - x1g - x2g) * 0.5f;
    float dy = (y1 + y2 - y1g - y2g) * 0.5f;
    float rho2 = dx * dx + dy * dy;
    float diou = 1.f - iou + rho2 / diag;
    float dd = atan_g - atan_p;
    const float CV = (float)(4.0 / (M_PI * M_PI));
    float v = CV * (dd * dd);
    float alpha = v / (1.f - iou + v + 1e-7f);
    return diou + alpha * v;
}

// ---------- K0: zero neg buckets + precompute GT geometry/labels ----------

__global__ __launch_bounds__(128) void init_kernel(
        const float* __restrict__ targets, double* __restrict__ buckets,
        float* __restrict__ gtab, int* __restrict__ larr) {
    int t = threadIdx.x;           // 128 = 4 b x 32 m
    if (t < 64) buckets[t] = 0.0;
    int b = t >> 5, m = t & 31;
    const float* gt = targets + (size_t)(b * NGT + m) * ROW;
    float xc = gt[0], yc = gt[1], w = gt[2], h = gt[3];
    float x1 = xc - w * 0.5f, y1 = yc - h * 0.5f;
    float x2 = xc + w * 0.5f, y2 = yc + h * 0.5f;
    float* gp = gtab + (size_t)(b * NGT + m) * 8;
    gp[0] = x1; gp[1] = y1; gp[2] = x2; gp[3] = y2;
    gp[4] = atanf((x2 - x1) / (y2 - y1));
    int lab = 0;
    for (int c = 0; c < NCLS; ++c) {
        if (gt[5 + c] > 0.5f) { lab = c; break; }
    }
    larr[b * NGT + m] = lab;
}

// ---------- K1: wave-per-pred S0 (coalesced class reads) + neg sum ----------

__global__ __launch_bounds__(256) void s0_kernel(
        const float* __restrict__ outputs, float* __restrict__ s0arr,
        double* __restrict__ buckets) {
    __shared__ double s_neg[4];
    int b = blockIdx.y;
    int wid = threadIdx.x >> 6, lane = threadIdx.x & 63;
    int n = blockIdx.x * 4 + wid;              // gridDim.x = 2100, exact
    const float* pr = outputs + (size_t)(b * NPRED + n) * ROW;

    float s = focal_t(pr[5 + lane], 0.f);      // classes lane and lane+64
    if (lane < 16) s += focal_t(pr[69 + lane], 0.f);
    #pragma unroll
    for (int off = 32; off >= 1; off >>= 1) s += __shfl_xor(s, off);

    if (lane == 0) {
        s0arr[b * NPRED + n] = s;
        s_neg[wid] = (double)focal_t(pr[4], 0.f);
    }
    __syncthreads();
    if (threadIdx.x == 0) {
        double t = s_neg[0] + s_neg[1] + s_neg[2] + s_neg[3];
        atomicAdd(&buckets[blockIdx.x & 63], t);
    }
}

// ---------- K2: cost matrix + per-(row,segment) minima, m split 4-way ----------

__global__ __launch_bounds__(256) void cost_kernel(
        const float* __restrict__ outputs, const float* __restrict__ s0arr,
        const float* __restrict__ gtab, const int* __restrict__ larr,
        float* __restrict__ costT, float* __restrict__ segval,
        int* __restrict__ segidx) {
    int b = blockIdx.z;
    int mbase = blockIdx.y * 8;
    int tid = threadIdx.x;
    int n = blockIdx.x * 256 + tid;
    bool valid = (n < NPRED);
    int seg = n >> 6;

    const float* pr = outputs + (size_t)(b * NPRED + (valid ? n : 0)) * ROW;
    float x1 = 0.f, y1 = 0.f, x2 = 0.f, y2 = 0.f, atan_p = 0.f, S0 = 0.f;
    if (valid) {
        float xc = pr[0], yc = pr[1], w = pr[2], h = pr[3];
        x1 = xc - w * 0.5f; y1 = yc - h * 0.5f;
        x2 = xc + w * 0.5f; y2 = yc + h * 0.5f;
        atan_p = atanf((x2 - x1) / (y2 - y1));
        S0 = s0arr[b * NPRED + n];
    }

    #pragma unroll
    for (int k = 0; k < 8; ++k) {
        int m = mbase + k;
        const float* gp = gtab + (size_t)(b * NGT + m) * 8;
        float cost = INFINITY;
        if (valid) {
            float cc = ciou_f(x1, y1, x2, y2, gp[0], gp[1], gp[2], gp[3],
                              atan_p, gp[4]);
            int lab = larr[b * NGT + m];
            float xl = pr[5 + lab];
            cost = cc + (S0 - focal_t(xl, 0.f) + focal_t(xl, 1.f)) / 80.f;
            costT[(size_t)(b * NGT + m) * NPRED + n] = cost;
        }
        float v = cost; int ci = valid ? n : NPRED;
        #pragma unroll
        for (int off = 32; off >= 1; off >>= 1) {
            float ov = __shfl_xor(v, off);
            int oi = __shfl_xor(ci, off);
            if (ov < v || (ov == v && oi < ci)) { v = ov; ci = oi; }
        }
        if ((tid & 63) == 0) {
            segval[(size_t)(b * NGT + m) * NSEG + seg] = v;
            segidx[(size_t)(b * NGT + m) * NSEG + seg] = ci;
        }
    }
}

// ---------- K3: assignment, single wave per batch ----------
// Same effective semantics as the reference "hungarian" (round-0 note):
// per GT row in order, (value, lowest-col) argmin over non-poisoned columns;
// on collision poison contested col then walk columns ascending, poisoning
// assigned ones, taking the first free.
// Parallel rowmin prologue + LAZY segment repair (only when a row's cached
// argmin column has been poisoned). Poisoning only removes columns, so a
// non-poisoned cached argmin stays exact (incl. first-index tie-break).

__global__ __launch_bounds__(64) void assign_kernel(
        const float* __restrict__ costT, const float* __restrict__ segval,
        const int* __restrict__ segidx, int* __restrict__ midx) {
    int b = blockIdx.x;
    int lane = threadIdx.x;
    __shared__ float sv[NGT * NSEGP];
    __shared__ int   si[NGT * NSEGP];
    __shared__ float rmv[NGT];
    __shared__ int   rmi[NGT];
    __shared__ unsigned char state[8464];   // 0 free, 1 assigned, 2 poisoned
    __shared__ int s_midx[NGT];

    // tables global -> LDS (padded row stride)
    for (int k = lane; k < NGT * NSEG; k += 64) {
        int r = k / NSEG, s = k - r * NSEG;
        sv[r * NSEGP + s] = segval[(size_t)b * NGT * NSEG + k];
        si[r * NSEGP + s] = segidx[(size_t)b * NGT * NSEG + k];
    }
    unsigned int* st32 = (unsigned int*)state;
    for (int k = lane; k < 8464 / 4; k += 64) st32[k] = 0u;

    // parallel rowmin: lane handles half the segments of row (lane&31)
    {
        int r = lane & 31;
        int half = lane >> 5;
        float v = INFINITY; int ci = NPRED;
        int s0 = half * 66;
        for (int s = s0; s < s0 + 66; ++s) {
            float vv = sv[r * NSEGP + s];
            int ii = si[r * NSEGP + s];
            if (vv < v || (vv == v && ii < ci)) { v = vv; ci = ii; }
        }
        float ov = __shfl_xor(v, 32);
        int oi = __shfl_xor(ci, 32);
        if (ov < v || (ov == v && oi < ci)) { v = ov; ci = oi; }
        if (half == 0) { rmv[r] = v; rmi[r] = ci; }
    }

    const float* C = costT + (size_t)b * NGT * NPRED;

    for (int i = 0; i < NGT; ++i) {
        int j1 = rmi[i];
        if (state[j1] == 2) {
            // lazy repair: fix row i's segments whose cached argmin is poisoned
            for (int k0 = 0; k0 < NSEG; k0 += 64) {
                int s = k0 + lane;
                int ii0 = (s < NSEG) ? si[i * NSEGP + s] : NPRED;
                bool inval = (s < NSEG) && (ii0 < NPRED) && (state[ii0] == 2);
                unsigned long long im = __ballot(inval);
                while (im) {
                    int sg = k0 + (__ffsll(im) - 1);
                    im &= im - 1;
                    int col = (sg << 6) + lane;
                    bool cvld = (col < NPRED) && (state[col] != 2);
                    float vv = cvld ? C[(size_t)i * NPRED + col] : INFINITY;
                    int ci2 = cvld ? col : NPRED;
                    #pragma unroll
                    for (int off = 32; off >= 1; off >>= 1) {
                        float ov = __shfl_xor(vv, off);
                        int oi = __shfl_xor(ci2, off);
                        if (ov < vv || (ov == vv && oi < ci2)) { vv = ov; ci2 = oi; }
                    }
                    if (lane == 0) { sv[i * NSEGP + sg] = vv; si[i * NSEGP + sg] = ci2; }
                }
            }
            // rescan the 132-entry table for row i
            float v = INFINITY; int ci = NPRED;
            for (int s = lane; s < NSEG; s += 64) {
                float vv = sv[i * NSEGP + s]; int ii = si[i * NSEGP + s];
                if (vv < v || (vv == v && ii < ci)) { v = vv; ci = ii; }
            }
            #pragma unroll
            for (int off = 32; off >= 1; off >>= 1) {
                float ov = __shfl_xor(v, off);
                int oi = __shfl_xor(ci, off);
                if (ov < v || (ov == v && oi < ci)) { v = ov; ci = oi; }
            }
            j1 = ci;
        }
        int st = state[j1];
        if (st == 0) {
            if (lane == 0) { state[j1] = 1; s_midx[i] = j1; }
        } else {
            // collision: poison j1, walk to first free col poisoning assigned
            if (lane == 0) state[j1] = 2;
            int jf = 0;
            for (int k0 = 0; k0 < NPRED; k0 += 64) {
                int col = k0 + lane;
                unsigned long long mask = __ballot(col < NPRED && state[col] == 0);
                if (mask) { jf = k0 + (__ffsll(mask) - 1); break; }
            }
            for (int j = lane; j < jf; j += 64) {
                if (state[j] == 1) state[j] = 2;
            }
            if (lane == 0) { state[jf] = 1; s_midx[i] = jf; }
        }
    }
    if (lane < NGT) midx[b * NGT + lane] = s_midx[lane];
}

// ---------- K4: finalize ----------

__global__ __launch_bounds__(128) void finalize_kernel(
        const float* __restrict__ outputs, const float* __restrict__ targets,
        const int* __restrict__ midx, const double* __restrict__ buckets,
        float* __restrict__ out) {
    __shared__ float s_siou[128], s_cls[128], s_adj[128];
    int t = threadIdx.x;
    int b = t >> 5, m = t & 31;

    const float* gt = targets + (size_t)(b * NGT + m) * ROW;
    int j = midx[b * NGT + m];
    const float* pr = outputs + (size_t)(b * NPRED + j) * ROW;

    float xc = pr[0], yc = pr[1], w = pr[2], h = pr[3];
    float x1 = xc - w * 0.5f, y1 = yc - h * 0.5f;
    float x2 = xc + w * 0.5f, y2 = yc + h * 0.5f;
    float atan_p = atanf((x2 - x1) / (y2 - y1));
    float gxc = gt[0], gyc = gt[1], gw = gt[2], gh = gt[3];
    float x1g = gxc - gw * 0.5f, y1g = gyc - gh * 0.5f;
    float x2g = gxc + gw * 0.5f, y2g = gyc + gh * 0.5f;
    float atan_g = atanf((x2g - x1g) / (y2g - y1g));

    s_siou[t] = ciou_f(x1, y1, x2, y2, x1g, y1g, x2g, y2g, atan_p, atan_g);

    float cls_sum = 0.f;
    for (int c = 0; c < NCLS; ++c) cls_sum += focal_t(pr[5 + c], gt[5 + c]);
    s_cls[t] = cls_sum / 80.f;

    float conf = pr[4];
    s_adj[t] = focal_t(conf, 1.f) - focal_t(conf, 0.f);
    __syncthreads();

    if (t == 0) {
        double nsum = 0.0;
        for (int k = 0; k < 64; ++k) nsum += buckets[k];
        double ssum = 0.0, csum = 0.0, asum = 0.0;
        for (int k = 0; k < 128; ++k) {
            ssum += (double)s_siou[k];
            csum += (double)s_cls[k];
            asum += (double)s_adj[k];
        }
        float siou = (float)(ssum / 128.0);
        float cls  = (float)(csum / 128.0);
        float obj  = (float)((nsum + asum) / (double)(NB * NPRED));
        out[0] = 2.0f * siou + 2.0f * obj + 2.0f * cls;
        out[1] = siou;
        out[2] = obj;
        out[3] = cls;
    }
}

// ---------- launch ----------

extern "C" void kernel_launch(void* const* d_in, const int* in_sizes, int n_in,
                              void* d_out, int out_size, void* d_ws, size_t ws_size,
                              hipStream_t stream) {
    const float* outputs = (const float*)d_in[0];
    const float* targets = (const float*)d_in[1];
    float* out = (float*)d_out;

    char* ws = (char*)d_ws;
    double* buckets = (double*)ws;                      // 64*8 = 512 B
    int* midx = (int*)(ws + 512);                       // 512 B
    float* gtab = (float*)(ws + 1024);                  // 4096 B
    int* larr = (int*)(ws + 5120);                      // 512 B
    float* s0arr = (float*)(ws + 6144);                 // 134400 B
    float* segval = (float*)(ws + 140544);              // 67584 B
    int* segidx = (int*)(ws + 208128);                  // 67584 B
    float* costT = (float*)(ws + 275712);               // 4300800 B

    init_kernel<<<1, 128, 0, stream>>>(targets, buckets, gtab, larr);

    dim3 g1(NPRED / 4, NB);                             // 2100 x 4, wave-per-pred
    s0_kernel<<<g1, 256, 0, stream>>>(outputs, s0arr, buckets);

    dim3 g2((NPRED + 255) / 256, NGT / 8, NB);          // 33 x 4 x 4
    cost_kernel<<<g2, 256, 0, stream>>>(outputs, s0arr, gtab, larr,
                                        costT, segval, segidx);

    assign_kernel<<<NB, 64, 0, stream>>>(costT, segval, segidx, midx);

    finalize_kernel<<<1, 128, 0, stream>>>(outputs, targets, midx, buckets, out);
}

// Round 5
// 100.817 us; speedup vs baseline: 1.7021x; 1.2650x over previous
//
#include <hip/hip_runtime.h>
#include <math.h>

#define NB 4
#define NPRED 8400
#define NGT 32
#define NCLS 80
#define ROW 85
#define NSEG 132    // ceil(8400/64)
#define NSEGP 133   // padded LDS row stride

// ---------- math helpers (mirror reference fp32 op order) ----------

__device__ __forceinline__ float focal_t(float x, float t) {
    float p = 1.f / (1.f + expf(-x));
    float ce = (fmaxf(x, 0.f) + log1pf(expf(-fabsf(x)))) - x * t; // logaddexp(0,x) - x*t
    float pt = p * t + (1.f - p) * (1.f - t);
    float ompt = 1.f - pt;
    float loss = ce * (ompt * ompt);              // GAMMA=2
    float at = 0.25f * t + 0.75f * (1.f - t);     // ALPHA=0.25
    return at * loss;
}

__device__ __forceinline__ float ciou_f(float x1, float y1, float x2, float y2,
                                        float x1g, float y1g, float x2g, float y2g,
                                        float atan_p, float atan_g) {
    float w1 = x2 - x1, h1 = y2 - y1;
    float wg = x2g - x1g, hg = y2g - y1g;
    float iw = fmaxf(fminf(x2, x2g) - fmaxf(x1, x1g), 0.f);
    float ih = fmaxf(fminf(y2, y2g) - fmaxf(y1, y1g), 0.f);
    float inter = iw * ih;
    float uni = w1 * h1 + wg * hg - inter;
    float iou = inter / (uni + 1e-7f);
    float cw = fmaxf(x2, x2g) - fminf(x1, x1g);
    float ch = fmaxf(y2, y2g) - fminf(y1, y1g);
    float diag = cw * cw + ch * ch + 1e-7f;
    float dx = (x1 + x2 - x1g - x2g) * 0.5f;
    float dy = (y1 + y2 - y1g - y2g) * 0.5f;
    float rho2 = dx * dx + dy * dy;
    float diou = 1.f - iou + rho2 / diag;
    float dd = atan_g - atan_p;
    const float CV = (float)(4.0 / (M_PI * M_PI));
    float v = CV * (dd * dd);
    float alpha = v / (1.f - iou + v + 1e-7f);
    return diou + alpha * v;
}

// ---------- K0: zero neg buckets + precompute GT geometry/labels ----------

__global__ __launch_bounds__(128) void init_kernel(
        const float* __restrict__ targets, double* __restrict__ buckets,
        float* __restrict__ gtab, int* __restrict__ larr) {
    int t = threadIdx.x;           // 128 = 4 b x 32 m
    if (t < 64) buckets[t] = 0.0;
    int b = t >> 5, m = t & 31;
    const float* gt = targets + (size_t)(b * NGT + m) * ROW;
    float xc = gt[0], yc = gt[1], w = gt[2], h = gt[3];
    float x1 = xc - w * 0.5f, y1 = yc - h * 0.5f;
    float x2 = xc + w * 0.5f, y2 = yc + h * 0.5f;
    float* gp = gtab + (size_t)(b * NGT + m) * 8;
    gp[0] = x1; gp[1] = y1; gp[2] = x2; gp[3] = y2;
    gp[4] = atanf((x2 - x1) / (y2 - y1));
    int lab = 0;
    for (int c = 0; c < NCLS; ++c) {
        if (gt[5 + c] > 0.5f) { lab = c; break; }
    }
    larr[b * NGT + m] = lab;
}

// ---------- K1: wave-per-pred S0 (coalesced class reads) + neg sum ----------

__global__ __launch_bounds__(256) void s0_kernel(
        const float* __restrict__ outputs, float* __restrict__ s0arr,
        double* __restrict__ buckets) {
    __shared__ double s_neg[4];
    int b = blockIdx.y;
    int wid = threadIdx.x >> 6, lane = threadIdx.x & 63;
    int n = blockIdx.x * 4 + wid;              // gridDim.x = 2100, exact
    const float* pr = outputs + (size_t)(b * NPRED + n) * ROW;

    float s = focal_t(pr[5 + lane], 0.f);      // classes lane and lane+64
    if (lane < 16) s += focal_t(pr[69 + lane], 0.f);
    #pragma unroll
    for (int off = 32; off >= 1; off >>= 1) s += __shfl_xor(s, off);

    if (lane == 0) {
        s0arr[b * NPRED + n] = s;
        s_neg[wid] = (double)focal_t(pr[4], 0.f);
    }
    __syncthreads();
    if (threadIdx.x == 0) {
        double t = s_neg[0] + s_neg[1] + s_neg[2] + s_neg[3];
        atomicAdd(&buckets[blockIdx.x & 63], t);
    }
}

// ---------- K2: cost matrix + per-(row,segment) minima, m split 4-way ----------

__global__ __launch_bounds__(256) void cost_kernel(
        const float* __restrict__ outputs, const float* __restrict__ s0arr,
        const float* __restrict__ gtab, const int* __restrict__ larr,
        float* __restrict__ costT, float* __restrict__ segval,
        int* __restrict__ segidx) {
    int b = blockIdx.z;
    int mbase = blockIdx.y * 8;
    int tid = threadIdx.x;
    int n = blockIdx.x * 256 + tid;
    bool valid = (n < NPRED);
    int seg = n >> 6;

    const float* pr = outputs + (size_t)(b * NPRED + (valid ? n : 0)) * ROW;
    float x1 = 0.f, y1 = 0.f, x2 = 0.f, y2 = 0.f, atan_p = 0.f, S0 = 0.f;
    if (valid) {
        float xc = pr[0], yc = pr[1], w = pr[2], h = pr[3];
        x1 = xc - w * 0.5f; y1 = yc - h * 0.5f;
        x2 = xc + w * 0.5f; y2 = yc + h * 0.5f;
        atan_p = atanf((x2 - x1) / (y2 - y1));
        S0 = s0arr[b * NPRED + n];
    }

    #pragma unroll
    for (int k = 0; k < 8; ++k) {
        int m = mbase + k;
        const float* gp = gtab + (size_t)(b * NGT + m) * 8;
        float cost = INFINITY;
        if (valid) {
            float cc = ciou_f(x1, y1, x2, y2, gp[0], gp[1], gp[2], gp[3],
                              atan_p, gp[4]);
            int lab = larr[b * NGT + m];
            float xl = pr[5 + lab];
            cost = cc + (S0 - focal_t(xl, 0.f) + focal_t(xl, 1.f)) / 80.f;
            costT[(size_t)(b * NGT + m) * NPRED + n] = cost;
        }
        float v = cost; int ci = valid ? n : NPRED;
        #pragma unroll
        for (int off = 32; off >= 1; off >>= 1) {
            float ov = __shfl_xor(v, off);
            int oi = __shfl_xor(ci, off);
            if (ov < v || (ov == v && oi < ci)) { v = ov; ci = oi; }
        }
        if ((tid & 63) == 0) {
            segval[(size_t)(b * NGT + m) * NSEG + seg] = v;
            segidx[(size_t)(b * NGT + m) * NSEG + seg] = ci;
        }
    }
}

// ---------- K3: assignment, single wave per batch ----------
// Same effective semantics as the reference "hungarian" (round-0 note).
// Parallel rowmin prologue + LAZY segment repair.

__global__ __launch_bounds__(64) void assign_kernel(
        const float* __restrict__ costT, const float* __restrict__ segval,
        const int* __restrict__ segidx, int* __restrict__ midx) {
    int b = blockIdx.x;
    int lane = threadIdx.x;
    __shared__ float sv[NGT * NSEGP];
    __shared__ int   si[NGT * NSEGP];
    __shared__ float rmv[NGT];
    __shared__ int   rmi[NGT];
    __shared__ unsigned char state[8464];   // 0 free, 1 assigned, 2 poisoned
    __shared__ int s_midx[NGT];

    for (int k = lane; k < NGT * NSEG; k += 64) {
        int r = k / NSEG, s = k - r * NSEG;
        sv[r * NSEGP + s] = segval[(size_t)b * NGT * NSEG + k];
        si[r * NSEGP + s] = segidx[(size_t)b * NGT * NSEG + k];
    }
    unsigned int* st32 = (unsigned int*)state;
    for (int k = lane; k < 8464 / 4; k += 64) st32[k] = 0u;

    // parallel rowmin: lane handles half the segments of row (lane&31)
    {
        int r = lane & 31;
        int half = lane >> 5;
        float v = INFINITY; int ci = NPRED;
        int s0 = half * 66;
        for (int s = s0; s < s0 + 66; ++s) {
            float vv = sv[r * NSEGP + s];
            int ii = si[r * NSEGP + s];
            if (vv < v || (vv == v && ii < ci)) { v = vv; ci = ii; }
        }
        float ov = __shfl_xor(v, 32);
        int oi = __shfl_xor(ci, 32);
        if (ov < v || (ov == v && oi < ci)) { v = ov; ci = oi; }
        if (half == 0) { rmv[r] = v; rmi[r] = ci; }
    }

    const float* C = costT + (size_t)b * NGT * NPRED;

    for (int i = 0; i < NGT; ++i) {
        int j1 = rmi[i];
        if (state[j1] == 2) {
            // lazy repair: fix row i's segments whose cached argmin is poisoned
            for (int k0 = 0; k0 < NSEG; k0 += 64) {
                int s = k0 + lane;
                int ii0 = (s < NSEG) ? si[i * NSEGP + s] : NPRED;
                bool inval = (s < NSEG) && (ii0 < NPRED) && (state[ii0] == 2);
                unsigned long long im = __ballot(inval);
                while (im) {
                    int sg = k0 + (__ffsll(im) - 1);
                    im &= im - 1;
                    int col = (sg << 6) + lane;
                    bool cvld = (col < NPRED) && (state[col] != 2);
                    float vv = cvld ? C[(size_t)i * NPRED + col] : INFINITY;
                    int ci2 = cvld ? col : NPRED;
                    #pragma unroll
                    for (int off = 32; off >= 1; off >>= 1) {
                        float ov = __shfl_xor(vv, off);
                        int oi = __shfl_xor(ci2, off);
                        if (ov < vv || (ov == vv && oi < ci2)) { vv = ov; ci2 = oi; }
                    }
                    if (lane == 0) { sv[i * NSEGP + sg] = vv; si[i * NSEGP + sg] = ci2; }
                }
            }
            float v = INFINITY; int ci = NPRED;
            for (int s = lane; s < NSEG; s += 64) {
                float vv = sv[i * NSEGP + s]; int ii = si[i * NSEGP + s];
                if (vv < v || (vv == v && ii < ci)) { v = vv; ci = ii; }
            }
            #pragma unroll
            for (int off = 32; off >= 1; off >>= 1) {
                float ov = __shfl_xor(v, off);
                int oi = __shfl_xor(ci, off);
                if (ov < v || (ov == v && oi < ci)) { v = ov; ci = oi; }
            }
            j1 = ci;
        }
        int st = state[j1];
        if (st == 0) {
            if (lane == 0) { state[j1] = 1; s_midx[i] = j1; }
        } else {
            if (lane == 0) state[j1] = 2;
            int jf = 0;
            for (int k0 = 0; k0 < NPRED; k0 += 64) {
                int col = k0 + lane;
                unsigned long long mask = __ballot(col < NPRED && state[col] == 0);
                if (mask) { jf = k0 + (__ffsll(mask) - 1); break; }
            }
            for (int j = lane; j < jf; j += 64) {
                if (state[j] == 1) state[j] = 2;
            }
            if (lane == 0) { state[jf] = 1; s_midx[i] = jf; }
        }
    }
    if (lane < NGT) midx[b * NGT + lane] = s_midx[lane];
}

// ---------- K4: finalize — fully wave-parallel, no single-thread chains ----

__global__ __launch_bounds__(1024) void finalize_kernel(
        const float* __restrict__ outputs, const float* __restrict__ targets,
        const int* __restrict__ midx, const double* __restrict__ buckets,
        float* __restrict__ out) {
    __shared__ float s_siou[128], s_cls[128], s_adj[128];
    int tid = threadIdx.x;
    int w = tid >> 6, lane = tid & 63;

    // Phase A: threads 0..127 -> ciou + obj-adjust for pair (b,m)
    if (tid < 128) {
        int b = tid >> 5, m = tid & 31;
        const float* gt = targets + (size_t)(b * NGT + m) * ROW;
        int j = midx[b * NGT + m];
        const float* pr = outputs + (size_t)(b * NPRED + j) * ROW;

        float xc = pr[0], yc = pr[1], ww = pr[2], hh = pr[3];
        float x1 = xc - ww * 0.5f, y1 = yc - hh * 0.5f;
        float x2 = xc + ww * 0.5f, y2 = yc + hh * 0.5f;
        float atan_p = atanf((x2 - x1) / (y2 - y1));
        float gxc = gt[0], gyc = gt[1], gw = gt[2], gh = gt[3];
        float x1g = gxc - gw * 0.5f, y1g = gyc - gh * 0.5f;
        float x2g = gxc + gw * 0.5f, y2g = gyc + gh * 0.5f;
        float atan_g = atanf((x2g - x1g) / (y2g - y1g));

        s_siou[tid] = ciou_f(x1, y1, x2, y2, x1g, y1g, x2g, y2g, atan_p, atan_g);
        float conf = pr[4];
        s_adj[tid] = focal_t(conf, 1.f) - focal_t(conf, 0.f);
    }

    // Phase B: wave w handles pairs w*8..w*8+7; lane-parallel cls focal
    #pragma unroll
    for (int q = 0; q < 8; ++q) {
        int p = w * 8 + q;
        int b = p >> 5, m = p & 31;
        int j = midx[b * NGT + m];                 // uniform per wave: broadcast
        const float* pr = outputs + (size_t)(b * NPRED + j) * ROW;
        const float* gt = targets + (size_t)(b * NGT + m) * ROW;
        float s = focal_t(pr[5 + lane], gt[5 + lane]);
        if (lane < 16) s += focal_t(pr[69 + lane], gt[69 + lane]);
        #pragma unroll
        for (int off = 32; off >= 1; off >>= 1) s += __shfl_xor(s, off);
        if (lane == 0) s_cls[p] = s / 80.f;
    }
    __syncthreads();

    // Phase C: one wave, fixed-order tree reduce (deterministic)
    if (tid < 64) {
        double ns = buckets[tid];                  // one coalesced load
        double ss = (double)s_siou[tid] + (double)s_siou[tid + 64];
        double cs = (double)s_cls[tid] + (double)s_cls[tid + 64];
        double as = (double)s_adj[tid] + (double)s_adj[tid + 64];
        #pragma unroll
        for (int off = 32; off >= 1; off >>= 1) {
            ns += __shfl_xor(ns, off);
            ss += __shfl_xor(ss, off);
            cs += __shfl_xor(cs, off);
            as += __shfl_xor(as, off);
        }
        if (tid == 0) {
            float siou = (float)(ss / 128.0);
            float cls  = (float)(cs / 128.0);
            float obj  = (float)((ns + as) / (double)(NB * NPRED));
            out[0] = 2.0f * siou + 2.0f * obj + 2.0f * cls;
            out[1] = siou;
            out[2] = obj;
            out[3] = cls;
        }
    }
}

// ---------- launch ----------

extern "C" void kernel_launch(void* const* d_in, const int* in_sizes, int n_in,
                              void* d_out, int out_size, void* d_ws, size_t ws_size,
                              hipStream_t stream) {
    const float* outputs = (const float*)d_in[0];
    const float* targets = (const float*)d_in[1];
    float* out = (float*)d_out;

    char* ws = (char*)d_ws;
    double* buckets = (double*)ws;                      // 512 B
    int* midx = (int*)(ws + 512);                       // 512 B
    float* gtab = (float*)(ws + 1024);                  // 4096 B
    int* larr = (int*)(ws + 5120);                      // 512 B
    float* s0arr = (float*)(ws + 6144);                 // 134400 B
    float* segval = (float*)(ws + 140544);              // 67584 B
    int* segidx = (int*)(ws + 208128);                  // 67584 B
    float* costT = (float*)(ws + 275712);               // 4300800 B

    init_kernel<<<1, 128, 0, stream>>>(targets, buckets, gtab, larr);

    dim3 g1(NPRED / 4, NB);                             // 2100 x 4, wave-per-pred
    s0_kernel<<<g1, 256, 0, stream>>>(outputs, s0arr, buckets);

    dim3 g2((NPRED + 255) / 256, NGT / 8, NB);          // 33 x 4 x 4
    cost_kernel<<<g2, 256, 0, stream>>>(outputs, s0arr, gtab, larr,
                                        costT, segval, segidx);

    assign_kernel<<<NB, 64, 0, stream>>>(costT, segval, segidx, midx);

    finalize_kernel<<<1, 1024, 0, stream>>>(outputs, targets, midx, buckets, out);
}

// Round 6
// 86.768 us; speedup vs baseline: 1.9776x; 1.1619x over previous
//
#include <hip/hip_runtime.h>
#include <math.h>

#define NB 4
#define NPRED 8400
#define NGT 32
#define NCLS 80
#define ROW 85
#define NSEG 132    // ceil(8400/64); last segment has 16 preds
#define NSEGP 133   // padded LDS row stride

// ---------- math helpers (mirror reference fp32 op order) ----------

__device__ __forceinline__ float focal_t(float x, float t) {
    float p = 1.f / (1.f + expf(-x));
    float ce = (fmaxf(x, 0.f) + log1pf(expf(-fabsf(x)))) - x * t; // logaddexp(0,x) - x*t
    float pt = p * t + (1.f - p) * (1.f - t);
    float ompt = 1.f - pt;
    float loss = ce * (ompt * ompt);              // GAMMA=2
    float at = 0.25f * t + 0.75f * (1.f - t);     // ALPHA=0.25
    return at * loss;
}

__device__ __forceinline__ float ciou_f(float x1, float y1, float x2, float y2,
                                        float x1g, float y1g, float x2g, float y2g,
                                        float atan_p, float atan_g) {
    float w1 = x2 - x1, h1 = y2 - y1;
    float wg = x2g - x1g, hg = y2g - y1g;
    float iw = fmaxf(fminf(x2, x2g) - fmaxf(x1, x1g), 0.f);
    float ih = fmaxf(fminf(y2, y2g) - fmaxf(y1, y1g), 0.f);
    float inter = iw * ih;
    float uni = w1 * h1 + wg * hg - inter;
    float iou = inter / (uni + 1e-7f);
    float cw = fmaxf(x2, x2g) - fminf(x1, x1g);
    float ch = fmaxf(y2, y2g) - fminf(y1, y1g);
    float diag = cw * cw + ch * ch + 1e-7f;
    float dx = (x1 + x2 - x1g - x2g) * 0.5f;
    float dy = (y1 + y2 - y1g - y2g) * 0.5f;
    float rho2 = dx * dx + dy * dy;
    float diou = 1.f - iou + rho2 / diag;
    float dd = atan_g - atan_p;
    const float CV = (float)(4.0 / (M_PI * M_PI));
    float v = CV * (dd * dd);
    float alpha = v / (1.f - iou + v + 1e-7f);
    return diou + alpha * v;
}

// ---------- K0: zero neg buckets + precompute GT geometry/labels ----------

__global__ __launch_bounds__(128) void init_kernel(
        const float* __restrict__ targets, double* __restrict__ buckets,
        float* __restrict__ gtab, int* __restrict__ larr) {
    int t = threadIdx.x;           // 128 = 4 b x 32 m
    if (t < 64) buckets[t] = 0.0;
    int b = t >> 5, m = t & 31;
    const float* gt = targets + (size_t)(b * NGT + m) * ROW;
    float xc = gt[0], yc = gt[1], w = gt[2], h = gt[3];
    float x1 = xc - w * 0.5f, y1 = yc - h * 0.5f;
    float x2 = xc + w * 0.5f, y2 = yc + h * 0.5f;
    float* gp = gtab + (size_t)(b * NGT + m) * 8;
    gp[0] = x1; gp[1] = y1; gp[2] = x2; gp[3] = y2;
    gp[4] = atanf((x2 - x1) / (y2 - y1));
    int lab = 0;
    for (int c = 0; c < NCLS; ++c) {
        if (gt[5 + c] > 0.5f) { lab = c; break; }
    }
    larr[b * NGT + m] = lab;
}

// ---------- K1: fused S0 + cost + segment minima (no costT materialized) ---
// Block = (segment sg of 64 preds, batch b). outputs read ONCE, coalesced.

__global__ __launch_bounds__(256) void fused_kernel(
        const float* __restrict__ outputs, const float* __restrict__ gtab,
        const int* __restrict__ larr, float* __restrict__ s0arr,
        float* __restrict__ segval, int* __restrict__ segidx,
        double* __restrict__ buckets) {
    int sg = blockIdx.x;                    // 0..131
    int b  = blockIdx.y;
    int tid = threadIdx.x;
    int p0 = sg * 64;
    int nv = (sg == NSEG - 1) ? (NPRED - (NSEG - 1) * 64) : 64;   // 16 or 64

    __shared__ float rows[64 * ROW];        // 21760 B, stride 85 (odd) -> conflict-free
    __shared__ float s_part[4 * 64];
    __shared__ float s_s0[64];
    __shared__ float s_gt[NGT * 8];
    __shared__ int   s_lab[NGT];

    // stage pred rows coalesced (contiguous nv*85 floats)
    const float* src = outputs + ((size_t)b * NPRED + p0) * ROW;
    int cnt = nv * ROW;
    for (int k = tid; k < cnt; k += 256) rows[k] = src[k];
    if (tid < NGT * 8) s_gt[tid] = gtab[b * NGT * 8 + tid];
    if (tid < NGT) s_lab[tid] = larr[b * NGT + tid];
    __syncthreads();

    // S0: pred = tid&63, chunk = tid>>6 covers 20 classes
    {
        int pred = tid & 63, chunk = tid >> 6;
        float s = 0.f;
        if (pred < nv) {
            const float* r = rows + pred * ROW;
            int c0 = chunk * 20;
            #pragma unroll
            for (int c = 0; c < 20; ++c) s += focal_t(r[5 + c0 + c], 0.f);
        }
        s_part[chunk * 64 + pred] = s;
    }
    __syncthreads();
    if (tid < 64) {
        float s = s_part[tid] + s_part[64 + tid] + s_part[128 + tid] + s_part[192 + tid];
        s_s0[tid] = s;
        if (tid < nv) s0arr[b * NPRED + p0 + tid] = s;
        // neg objectness focal for this segment (wave 0)
        double ng = (tid < nv) ? (double)focal_t(rows[tid * ROW + 4], 0.f) : 0.0;
        #pragma unroll
        for (int off = 32; off >= 1; off >>= 1) ng += __shfl_xor(ng, off);
        if (tid == 0) atomicAdd(&buckets[sg & 63], ng);
    }
    __syncthreads();

    // cost + segment minima: wave w -> GT rows w*8..w*8+7, lane = pred
    int w = tid >> 6, lane = tid & 63;
    bool valid = lane < nv;
    float x1 = 0.f, y1 = 0.f, x2 = 0.f, y2 = 0.f, atan_p = 0.f, S0 = 0.f;
    const float* r = rows + lane * ROW;
    if (valid) {
        float xc = r[0], yc = r[1], ww = r[2], hh = r[3];
        x1 = xc - ww * 0.5f; y1 = yc - hh * 0.5f;
        x2 = xc + ww * 0.5f; y2 = yc + hh * 0.5f;
        atan_p = atanf((x2 - x1) / (y2 - y1));
        S0 = s_s0[lane];
    }
    #pragma unroll
    for (int q = 0; q < 8; ++q) {
        int m = w * 8 + q;
        const float* gp = s_gt + m * 8;
        float cost = INFINITY;
        if (valid) {
            float cc = ciou_f(x1, y1, x2, y2, gp[0], gp[1], gp[2], gp[3],
                              atan_p, gp[4]);
            float xl = r[5 + s_lab[m]];
            cost = cc + (S0 - focal_t(xl, 0.f) + focal_t(xl, 1.f)) / 80.f;
        }
        float v = cost; int ci = valid ? (p0 + lane) : NPRED;
        #pragma unroll
        for (int off = 32; off >= 1; off >>= 1) {
            float ov = __shfl_xor(v, off);
            int oi = __shfl_xor(ci, off);
            if (ov < v || (ov == v && oi < ci)) { v = ov; ci = oi; }
        }
        if (lane == 0) {
            segval[(size_t)(b * NGT + m) * NSEG + sg] = v;
            segidx[(size_t)(b * NGT + m) * NSEG + sg] = ci;
        }
    }
}

// ---------- K2: assignment, single wave per batch ----------
// Same effective semantics as the reference "hungarian" (round-0 note).
// Parallel rowmin prologue + LAZY repair; repair RECOMPUTES the segment's
// costs from outputs/s0arr (same inlined math as fused_kernel -> same bits).

__global__ __launch_bounds__(64) void assign_kernel(
        const float* __restrict__ outputs, const float* __restrict__ s0arr,
        const float* __restrict__ gtab, const int* __restrict__ larr,
        const float* __restrict__ segval, const int* __restrict__ segidx,
        int* __restrict__ midx) {
    int b = blockIdx.x;
    int lane = threadIdx.x;
    __shared__ float sv[NGT * NSEGP];
    __shared__ int   si[NGT * NSEGP];
    __shared__ float s_gt[NGT * 8];
    __shared__ int   s_lab[NGT];
    __shared__ int   rmi[NGT];
    __shared__ unsigned char state[8464];   // 0 free, 1 assigned, 2 poisoned
    __shared__ int s_midx[NGT];

    for (int k = lane; k < NGT * NSEG; k += 64) {
        int r = k / NSEG, s = k - r * NSEG;
        sv[r * NSEGP + s] = segval[(size_t)b * NGT * NSEG + k];
        si[r * NSEGP + s] = segidx[(size_t)b * NGT * NSEG + k];
    }
    for (int k = lane; k < NGT * 8; k += 64) s_gt[k] = gtab[b * NGT * 8 + k];
    if (lane < NGT) s_lab[lane] = larr[b * NGT + lane];
    unsigned int* st32 = (unsigned int*)state;
    for (int k = lane; k < 8464 / 4; k += 64) st32[k] = 0u;

    // parallel rowmin: lane handles half the segments of row (lane&31)
    {
        int r = lane & 31;
        int half = lane >> 5;
        float v = INFINITY; int ci = NPRED;
        int s0 = half * 66;
        for (int s = s0; s < s0 + 66; ++s) {
            float vv = sv[r * NSEGP + s];
            int ii = si[r * NSEGP + s];
            if (vv < v || (vv == v && ii < ci)) { v = vv; ci = ii; }
        }
        float ov = __shfl_xor(v, 32);
        int oi = __shfl_xor(ci, 32);
        if (ov < v || (ov == v && oi < ci)) { v = ov; ci = oi; }
        if (half == 0) rmi[r] = ci;
    }

    const float* Ob = outputs + (size_t)b * NPRED * ROW;
    const float* S0b = s0arr + (size_t)b * NPRED;

    for (int i = 0; i < NGT; ++i) {
        int j1 = rmi[i];
        if (state[j1] == 2) {
            // lazy repair: recompute segments of row i whose cached argmin is poisoned
            const float* gp = s_gt + i * 8;
            int lab = s_lab[i];
            for (int k0 = 0; k0 < NSEG; k0 += 64) {
                int s = k0 + lane;
                int ii0 = (s < NSEG) ? si[i * NSEGP + s] : NPRED;
                bool inval = (s < NSEG) && (ii0 < NPRED) && (state[ii0] == 2);
                unsigned long long im = __ballot(inval);
                while (im) {
                    int sg = k0 + (__ffsll(im) - 1);
                    im &= im - 1;
                    int col = (sg << 6) + lane;
                    bool cvld = (col < NPRED) && (state[col] != 2);
                    float vv = INFINITY; int ci2 = NPRED;
                    if (cvld) {
                        const float* pr = Ob + (size_t)col * ROW;
                        float xc = pr[0], yc = pr[1], ww = pr[2], hh = pr[3];
                        float x1 = xc - ww * 0.5f, y1 = yc - hh * 0.5f;
                        float x2 = xc + ww * 0.5f, y2 = yc + hh * 0.5f;
                        float atan_p = atanf((x2 - x1) / (y2 - y1));
                        float cc = ciou_f(x1, y1, x2, y2, gp[0], gp[1], gp[2], gp[3],
                                          atan_p, gp[4]);
                        float xl = pr[5 + lab];
                        float S0 = S0b[col];
                        vv = cc + (S0 - focal_t(xl, 0.f) + focal_t(xl, 1.f)) / 80.f;
                        ci2 = col;
                    }
                    #pragma unroll
                    for (int off = 32; off >= 1; off >>= 1) {
                        float ov = __shfl_xor(vv, off);
                        int oi = __shfl_xor(ci2, off);
                        if (ov < vv || (ov == vv && oi < ci2)) { vv = ov; ci2 = oi; }
                    }
                    if (lane == 0) { sv[i * NSEGP + sg] = vv; si[i * NSEGP + sg] = ci2; }
                }
            }
            // rescan the 132-entry table for row i
            float v = INFINITY; int ci = NPRED;
            for (int s = lane; s < NSEG; s += 64) {
                float vv = sv[i * NSEGP + s]; int ii = si[i * NSEGP + s];
                if (vv < v || (vv == v && ii < ci)) { v = vv; ci = ii; }
            }
            #pragma unroll
            for (int off = 32; off >= 1; off >>= 1) {
                float ov = __shfl_xor(v, off);
                int oi = __shfl_xor(ci, off);
                if (ov < v || (ov == v && oi < ci)) { v = ov; ci = oi; }
            }
            j1 = ci;
        }
        int st = state[j1];
        if (st == 0) {
            if (lane == 0) { state[j1] = 1; s_midx[i] = j1; }
        } else {
            if (lane == 0) state[j1] = 2;
            int jf = 0;
            for (int k0 = 0; k0 < NPRED; k0 += 64) {
                int col = k0 + lane;
                unsigned long long mask = __ballot(col < NPRED && state[col] == 0);
                if (mask) { jf = k0 + (__ffsll(mask) - 1); break; }
            }
            for (int j = lane; j < jf; j += 64) {
                if (state[j] == 1) state[j] = 2;
            }
            if (lane == 0) { state[jf] = 1; s_midx[i] = jf; }
        }
    }
    if (lane < NGT) midx[b * NGT + lane] = s_midx[lane];
}

// ---------- K3: finalize — fully wave-parallel ----------

__global__ __launch_bounds__(1024) void finalize_kernel(
        const float* __restrict__ outputs, const float* __restrict__ targets,
        const int* __restrict__ midx, const double* __restrict__ buckets,
        float* __restrict__ out) {
    __shared__ float s_siou[128], s_cls[128], s_adj[128];
    int tid = threadIdx.x;
    int w = tid >> 6, lane = tid & 63;

    if (tid < 128) {
        int b = tid >> 5, m = tid & 31;
        const float* gt = targets + (size_t)(b * NGT + m) * ROW;
        int j = midx[b * NGT + m];
        const float* pr = outputs + (size_t)(b * NPRED + j) * ROW;

        float xc = pr[0], yc = pr[1], ww = pr[2], hh = pr[3];
        float x1 = xc - ww * 0.5f, y1 = yc - hh * 0.5f;
        float x2 = xc + ww * 0.5f, y2 = yc + hh * 0.5f;
        float atan_p = atanf((x2 - x1) / (y2 - y1));
        float gxc = gt[0], gyc = gt[1], gw = gt[2], gh = gt[3];
        float x1g = gxc - gw * 0.5f, y1g = gyc - gh * 0.5f;
        float x2g = gxc + gw * 0.5f, y2g = gyc + gh * 0.5f;
        float atan_g = atanf((x2g - x1g) / (y2g - y1g));

        s_siou[tid] = ciou_f(x1, y1, x2, y2, x1g, y1g, x2g, y2g, atan_p, atan_g);
        float conf = pr[4];
        s_adj[tid] = focal_t(conf, 1.f) - focal_t(conf, 0.f);
    }

    #pragma unroll
    for (int q = 0; q < 8; ++q) {
        int p = w * 8 + q;
        int b = p >> 5, m = p & 31;
        int j = midx[b * NGT + m];
        const float* pr = outputs + (size_t)(b * NPRED + j) * ROW;
        const float* gt = targets + (size_t)(b * NGT + m) * ROW;
        float s = focal_t(pr[5 + lane], gt[5 + lane]);
        if (lane < 16) s += focal_t(pr[69 + lane], gt[69 + lane]);
        #pragma unroll
        for (int off = 32; off >= 1; off >>= 1) s += __shfl_xor(s, off);
        if (lane == 0) s_cls[p] = s / 80.f;
    }
    __syncthreads();

    if (tid < 64) {
        double ns = buckets[tid];
        double ss = (double)s_siou[tid] + (double)s_siou[tid + 64];
        double cs = (double)s_cls[tid] + (double)s_cls[tid + 64];
        double as = (double)s_adj[tid] + (double)s_adj[tid + 64];
        #pragma unroll
        for (int off = 32; off >= 1; off >>= 1) {
            ns += __shfl_xor(ns, off);
            ss += __shfl_xor(ss, off);
            cs += __shfl_xor(cs, off);
            as += __shfl_xor(as, off);
        }
        if (tid == 0) {
            float siou = (float)(ss / 128.0);
            float cls  = (float)(cs / 128.0);
            float obj  = (float)((ns + as) / (double)(NB * NPRED));
            out[0] = 2.0f * siou + 2.0f * obj + 2.0f * cls;
            out[1] = siou;
            out[2] = obj;
            out[3] = cls;
        }
    }
}

// ---------- launch ----------

extern "C" void kernel_launch(void* const* d_in, const int* in_sizes, int n_in,
                              void* d_out, int out_size, void* d_ws, size_t ws_size,
                              hipStream_t stream) {
    const float* outputs = (const float*)d_in[0];
    const float* targets = (const float*)d_in[1];
    float* out = (float*)d_out;

    char* ws = (char*)d_ws;
    double* buckets = (double*)ws;                      // 512 B
    int* midx = (int*)(ws + 512);                       // 512 B
    float* gtab = (float*)(ws + 1024);                  // 4096 B
    int* larr = (int*)(ws + 5120);                      // 512 B
    float* s0arr = (float*)(ws + 6144);                 // 134400 B
    float* segval = (float*)(ws + 140544);              // 67584 B
    int* segidx = (int*)(ws + 208128);                  // 67584 B

    init_kernel<<<1, 128, 0, stream>>>(targets, buckets, gtab, larr);

    dim3 g1(NSEG, NB);                                  // 132 x 4 segment blocks
    fused_kernel<<<g1, 256, 0, stream>>>(outputs, gtab, larr, s0arr,
                                         segval, segidx, buckets);

    assign_kernel<<<NB, 64, 0, stream>>>(outputs, s0arr, gtab, larr,
                                         segval, segidx, midx);

    finalize_kernel<<<1, 1024, 0, stream>>>(outputs, targets, midx, buckets, out);
}